// Round 3
// baseline (493.092 us; speedup 1.0000x reference)
//
#include <hip/hip_runtime.h>

#define EPSF 1e-8f

constexpr int D0 = 128;   // input dim
constexpr int R  = 256;   // random features
constexpr int D1 = 64;    // output dim
constexpr int BM = 32;    // rows per block
constexpr int NT = 256;   // threads per block (4 waves)

typedef __attribute__((ext_vector_type(8))) short  bf16x8;
typedef __attribute__((ext_vector_type(4))) float  f32x4;
typedef __attribute__((ext_vector_type(4))) uint   u32x4;

// ws layout (ushort elements): same as round 2 — works unchanged as A-frags
constexpr int WS_W1VAR = 32768;
constexpr int WS_W2MU  = 65536;
constexpr int WS_W2VAR = 81920;
constexpr int WS_W2SQ  = 98304;

__device__ __forceinline__ ushort f2bf(float x) {
    uint32_t u = __builtin_bit_cast(uint32_t, x);
    u += 0x7FFFu + ((u >> 16) & 1u);          // round-to-nearest-even
    return (ushort)(u >> 16);
}

// packed f32x2 -> bf16x2 (RNE), 1 VALU inst; non-volatile so scheduler may move
__device__ __forceinline__ uint cvt_pk_bf16(float lo, float hi) {
    uint r;
    asm("v_cvt_pk_bf16_f32 %0, %1, %2" : "=v"(r) : "v"(lo), "v"(hi));
    return r;
}

// --- pre-kernel: convert weights to bf16 in MFMA fragment order ------------
// frag: lane l, elem j -> W[row = base16 + (l&15)][k = k0 + (l>>4)*8 + j]
__global__ void convert_w(const float* __restrict__ W1mu,
                          const float* __restrict__ W1var,
                          const float* __restrict__ W2mu,
                          const float* __restrict__ W2var,
                          ushort* __restrict__ ws)
{
    int tid = blockIdx.x * 256 + threadIdx.x;
    if (tid < 8192) {                       // layer 1: 2 mats * 64 frags * 64 lanes
        int m    = tid >> 12;               // 0=mu 1=var
        int f    = (tid >> 6) & 63;         // frag = nt*4 + ks
        int lane = tid & 63;
        int nt = f >> 2, ks = f & 3;
        int col = nt * 16 + (lane & 15);    // rf index (W1 row)
        int k0  = ks * 32 + (lane >> 4) * 8;
        const float* src = (m ? W1var : W1mu) + (size_t)col * D0 + k0;
        ushort* dst = ws + (m ? WS_W1VAR : 0) + (size_t)(f * 64 + lane) * 8;
        #pragma unroll
        for (int j = 0; j < 8; ++j) dst[j] = f2bf(src[j]);
    } else if (tid < 8192 + 3 * 2048) {     // layer 2: 3 mats * 32 frags * 64 lanes
        int t2   = tid - 8192;
        int m    = t2 >> 11;                // 0=mu 1=var 2=mu^2
        int f    = (t2 >> 6) & 31;          // frag = nt*8 + ks
        int lane = t2 & 63;
        int nt = f >> 3, ks = f & 7;
        int col = nt * 16 + (lane & 15);    // d1 index (W2 row)
        int k0  = ks * 32 + (lane >> 4) * 8;
        const float* src = (m == 1 ? W2var : W2mu) + (size_t)col * R + k0;
        ushort* dst = ws + WS_W2MU + m * 16384 + (size_t)(f * 64 + lane) * 8;
        #pragma unroll
        for (int j = 0; j < 8; ++j) {
            float v = src[j];
            if (m == 2) v = v * v;
            dst[j] = f2bf(v);
        }
    }
}

// --- fused main kernel ------------------------------------------------------
// Operand-swapped: D = W·X^T, so per-lane C holds 4 consecutive rf/d1 for one
// X-row. A-frags = weights (from ws), B-frags = X / slabs.
__global__ __launch_bounds__(NT, 3)
void dgp_mfma(const float* __restrict__ X,
              const int*   __restrict__ Xidx,
              const ushort* __restrict__ ws,
              float* __restrict__ accM,
              float* __restrict__ accP)
{
    // 3 bf16 slabs [32][256], XOR-swizzled (16B granule): 48 KB -> 3 blocks/CU
    __shared__ ushort M1s[BM * R];
    __shared__ ushort T1s[BM * R];
    __shared__ ushort V1s[BM * R];

    const int t    = threadIdx.x;
    const int lane = t & 63;
    const int w    = t >> 6;         // wave 0..3
    const int row0 = blockIdx.x * BM;
    const int lcol = lane & 15;      // X-row within 16-tile (B-frag col / C col)
    const int lk   = lane >> 4;      // 0..3 (k-group / C row group)

    // hoist segment indices (one per lane per row-tile)
    int gidx[2];
    gidx[0] = Xidx[row0 + lcol];
    gidx[1] = Xidx[row0 + 16 + lcol];

    // ---------------- Layer 1: W1·X^T (mu) and W1var·(X^2)^T ----------------
    // wave w owns rf-tiles 4w..4w+3, both row-tiles
    f32x4 accm[2][4], accv[2][4];   // [rt][nt]
    #pragma unroll
    for (int rt = 0; rt < 2; ++rt)
        #pragma unroll
        for (int nt = 0; nt < 4; ++nt) {
            accm[rt][nt] = (f32x4)0.f;
            accv[rt][nt] = (f32x4)0.f;
        }

    #pragma unroll
    for (int ks = 0; ks < 4; ++ks) {
        bf16x8 xb[2], xq[2];
        #pragma unroll
        for (int rt = 0; rt < 2; ++rt) {
            const float* xp = X + (size_t)(row0 + rt * 16 + lcol) * D0 + ks * 32 + lk * 8;
            float4 a = *(const float4*)xp;
            float4 b = *(const float4*)(xp + 4);
            u32x4 um, uq;
            um[0] = cvt_pk_bf16(a.x, a.y);
            um[1] = cvt_pk_bf16(a.z, a.w);
            um[2] = cvt_pk_bf16(b.x, b.y);
            um[3] = cvt_pk_bf16(b.z, b.w);
            uq[0] = cvt_pk_bf16(a.x * a.x, a.y * a.y);
            uq[1] = cvt_pk_bf16(a.z * a.z, a.w * a.w);
            uq[2] = cvt_pk_bf16(b.x * b.x, b.y * b.y);
            uq[3] = cvt_pk_bf16(b.z * b.z, b.w * b.w);
            xb[rt] = __builtin_bit_cast(bf16x8, um);
            xq[rt] = __builtin_bit_cast(bf16x8, uq);
        }
        #pragma unroll
        for (int nt = 0; nt < 4; ++nt) {
            int f = (w * 4 + nt) * 4 + ks;
            bf16x8 amu = *(const bf16x8*)(ws + (size_t)(f * 64 + lane) * 8);
            bf16x8 avr = *(const bf16x8*)(ws + WS_W1VAR + (size_t)(f * 64 + lane) * 8);
            #pragma unroll
            for (int rt = 0; rt < 2; ++rt) {
                accm[rt][nt] = __builtin_amdgcn_mfma_f32_16x16x32_bf16(amu, xb[rt], accm[rt][nt], 0, 0, 0);
                accv[rt][nt] = __builtin_amdgcn_mfma_f32_16x16x32_bf16(avr, xq[rt], accv[rt][nt], 0, 0, 0);
            }
        }
    }

    // RF-ReLU epilogue: per lane 4 consecutive rf at one row -> b64 LDS writes
    const float SCALE  = 0.08838834764831845f;  // sqrt(2/256)
    const float SCALE2 = 0.0078125f;            // 2/256
    #pragma unroll
    for (int rt = 0; rt < 2; ++rt) {
        int xrow = rt * 16 + lcol;
        int swz  = (xrow & 7) << 3;             // 16B-granule XOR swizzle
        int rowb = xrow * 256;
        #pragma unroll
        for (int nt = 0; nt < 4; ++nt) {
            int rf0 = (w * 4 + nt) * 16 + lk * 4;
            float m1[4], v1[4], t1[4];
            #pragma unroll
            for (int i = 0; i < 4; ++i) {
                float om = accm[rt][nt][i];
                float ov = accv[rt][nt][i];
                bool pos = om > 0.f;
                m1[i] = pos ? SCALE  * om : 0.f;
                v1[i] = pos ? SCALE2 * ov : 0.f;
                t1[i] = fmaf(m1[i], m1[i], v1[i]);   // v1 + m1^2
            }
            uint2 pm, pt, pv;
            pm.x = cvt_pk_bf16(m1[0], m1[1]); pm.y = cvt_pk_bf16(m1[2], m1[3]);
            pt.x = cvt_pk_bf16(t1[0], t1[1]); pt.y = cvt_pk_bf16(t1[2], t1[3]);
            pv.x = cvt_pk_bf16(v1[0], v1[1]); pv.y = cvt_pk_bf16(v1[2], v1[3]);
            int idx = rowb + (rf0 ^ swz);
            *(uint2*)&M1s[idx] = pm;
            *(uint2*)&T1s[idx] = pt;
            *(uint2*)&V1s[idx] = pv;
        }
    }

    __syncthreads();

    // ---------------- Layer 2: W2·slab^T moment GEMMs (K=256) ---------------
    // wave w owns d1-tile w, both row-tiles
    f32x4 m2a[2], v2a[2];
    #pragma unroll
    for (int rt = 0; rt < 2; ++rt) { m2a[rt] = (f32x4)0.f; v2a[rt] = (f32x4)0.f; }

    #pragma unroll
    for (int ks = 0; ks < 8; ++ks) {
        int f = w * 8 + ks;
        bf16x8 amu = *(const bf16x8*)(ws + WS_W2MU  + (size_t)(f * 64 + lane) * 8);
        bf16x8 avr = *(const bf16x8*)(ws + WS_W2VAR + (size_t)(f * 64 + lane) * 8);
        bf16x8 asq = *(const bf16x8*)(ws + WS_W2SQ  + (size_t)(f * 64 + lane) * 8);
        #pragma unroll
        for (int rt = 0; rt < 2; ++rt) {
            int xrow = rt * 16 + lcol;
            int base = xrow * 256 + ((ks * 32 + lk * 8) ^ ((xrow & 7) << 3));
            bf16x8 bm = *(const bf16x8*)&M1s[base];
            bf16x8 bt = *(const bf16x8*)&T1s[base];
            bf16x8 bv = *(const bf16x8*)&V1s[base];
            m2a[rt] = __builtin_amdgcn_mfma_f32_16x16x32_bf16(amu, bm, m2a[rt], 0, 0, 0);
            v2a[rt] = __builtin_amdgcn_mfma_f32_16x16x32_bf16(avr, bt, v2a[rt], 0, 0, 0);
            v2a[rt] = __builtin_amdgcn_mfma_f32_16x16x32_bf16(asq, bv, v2a[rt], 0, 0, 0);
        }
    }

    // ---------------- Phase 3: precision-weighted scatter -------------------
    // per lane: 4 consecutive d1 at one row -> atomics in one 16B region
    const int d10 = w * 16 + lk * 4;
    #pragma unroll
    for (int rt = 0; rt < 2; ++rt) {
        float* pM = accM + (size_t)gidx[rt] * D1 + d10;
        float* pP = accP + (size_t)gidx[rt] * D1 + d10;
        #pragma unroll
        for (int i = 0; i < 4; ++i) {
            float p = 1.0f / (v2a[rt][i] + EPSF);
            atomicAdd(pP + i, p);
            atomicAdd(pM + i, p * m2a[rt][i]);
        }
    }
}

__global__ void dgp_finalize(float* __restrict__ accM,
                             float* __restrict__ accP, int total)
{
    int idx = blockIdx.x * blockDim.x + threadIdx.x;
    if (idx < total) {
        float var = 1.0f / (accP[idx] + EPSF);   // p_sum = seg_sum + EPS
        accP[idx] = var;                         // embedd_vars
        accM[idx] = accM[idx] * var;             // embedd_means
    }
}

extern "C" void kernel_launch(void* const* d_in, const int* in_sizes, int n_in,
                              void* d_out, int out_size, void* d_ws, size_t ws_size,
                              hipStream_t stream)
{
    const float* X     = (const float*)d_in[0];
    const int*   Xidx  = (const int*)d_in[1];
    const float* W1mu  = (const float*)d_in[2];
    const float* W1var = (const float*)d_in[3];
    const float* W2mu  = (const float*)d_in[4];
    const float* W2var = (const float*)d_in[5];

    const int N = in_sizes[0] / D0;            // 262144
    const int U = out_size / (2 * D1);         // 50000
    float* out  = (float*)d_out;
    float* accM = out;                          // means region
    float* accP = out + (size_t)U * D1;         // vars region
    ushort* ws  = (ushort*)d_ws;

    // harness does not re-poison between replays: re-zero accumulators
    hipMemsetAsync(d_out, 0, (size_t)out_size * sizeof(float), stream);

    convert_w<<<56, 256, 0, stream>>>(W1mu, W1var, W2mu, W2var, ws);

    dgp_mfma<<<N / BM, NT, 0, stream>>>(X, Xidx, ws, accM, accP);

    const int total = U * D1;
    dgp_finalize<<<(total + 255) / 256, 256, 0, stream>>>(accM, accP, total);
}

// Round 4
// 205.693 us; speedup vs baseline: 2.3972x; 2.3972x over previous
//
#include <hip/hip_runtime.h>

#define EPSF 1e-8f

constexpr int D0 = 128;   // input dim
constexpr int R  = 256;   // random features
constexpr int D1 = 64;    // output dim
constexpr int BM = 32;    // rows per block
constexpr int NT = 256;   // threads per block (4 waves)

typedef __attribute__((ext_vector_type(8))) short  bf16x8;
typedef __attribute__((ext_vector_type(4))) float  f32x4;
typedef __attribute__((ext_vector_type(4))) uint   u32x4;

// ws layout (ushort elements): bf16 weights in MFMA fragment order
constexpr int WS_W1VAR = 32768;
constexpr int WS_W2MU  = 65536;
constexpr int WS_W2VAR = 81920;
constexpr int WS_W2SQ  = 98304;

__device__ __forceinline__ ushort f2bf(float x) {
    uint32_t u = __builtin_bit_cast(uint32_t, x);
    u += 0x7FFFu + ((u >> 16) & 1u);          // round-to-nearest-even
    return (ushort)(u >> 16);
}

// packed f32x2 -> bf16x2 (RNE), 1 VALU inst
__device__ __forceinline__ uint cvt_pk_bf16(float lo, float hi) {
    uint r;
    asm("v_cvt_pk_bf16_f32 %0, %1, %2" : "=v"(r) : "v"(lo), "v"(hi));
    return r;
}

// --- pre-kernel: convert weights to bf16 in MFMA fragment order ------------
// frag: lane l, elem j -> W[row = base16 + (l&15)][k = k0 + (l>>4)*8 + j]
__global__ void convert_w(const float* __restrict__ W1mu,
                          const float* __restrict__ W1var,
                          const float* __restrict__ W2mu,
                          const float* __restrict__ W2var,
                          ushort* __restrict__ ws)
{
    int tid = blockIdx.x * 256 + threadIdx.x;
    if (tid < 8192) {                       // layer 1: 2 mats * 64 frags * 64 lanes
        int m    = tid >> 12;               // 0=mu 1=var
        int f    = (tid >> 6) & 63;         // frag = nt*4 + ks
        int lane = tid & 63;
        int nt = f >> 2, ks = f & 3;
        int col = nt * 16 + (lane & 15);    // rf index (W1 row)
        int k0  = ks * 32 + (lane >> 4) * 8;
        const float* src = (m ? W1var : W1mu) + (size_t)col * D0 + k0;
        ushort* dst = ws + (m ? WS_W1VAR : 0) + (size_t)(f * 64 + lane) * 8;
        #pragma unroll
        for (int j = 0; j < 8; ++j) dst[j] = f2bf(src[j]);
    } else if (tid < 8192 + 3 * 2048) {     // layer 2: 3 mats * 32 frags * 64 lanes
        int t2   = tid - 8192;
        int m    = t2 >> 11;                // 0=mu 1=var 2=mu^2
        int f    = (t2 >> 6) & 31;          // frag = nt*8 + ks
        int lane = t2 & 63;
        int nt = f >> 3, ks = f & 7;
        int col = nt * 16 + (lane & 15);    // d1 index (W2 row)
        int k0  = ks * 32 + (lane >> 4) * 8;
        const float* src = (m == 1 ? W2var : W2mu) + (size_t)col * R + k0;
        ushort* dst = ws + WS_W2MU + m * 16384 + (size_t)(f * 64 + lane) * 8;
        #pragma unroll
        for (int j = 0; j < 8; ++j) {
            float v = src[j];
            if (m == 2) v = v * v;
            dst[j] = f2bf(v);
        }
    }
}

// --- fused main kernel ------------------------------------------------------
// Operand-swapped GEMMs (D = W·X^T); scatter via LDS transpose so each atomic
// instruction is ONE wave-uniform row x 64 consecutive floats (256B dense).
__global__ __launch_bounds__(NT, 3)
void dgp_mfma(const float* __restrict__ X,
              const int*   __restrict__ Xidx,
              const ushort* __restrict__ ws,
              float* __restrict__ accM,
              float* __restrict__ accP)
{
    // one 48KB slab, aliased: phase A = 3 bf16 tiles [32][256] XOR-swizzled;
    // phase B = 2 f32 arrays [32][65] for the scatter transpose
    __shared__ __align__(16) ushort sh[3 * BM * R];
    ushort* M1s = sh;
    ushort* T1s = sh + BM * R;
    ushort* V1s = sh + 2 * BM * R;

    const int t    = threadIdx.x;
    const int lane = t & 63;
    const int w    = t >> 6;         // wave 0..3
    const int row0 = blockIdx.x * BM;
    const int lcol = lane & 15;      // X-row within 16-tile (B-frag col / C col)
    const int lk   = lane >> 4;      // 0..3 (k-group / C row group)

    // ---------------- Layer 1: W1·X^T (mu) and W1var·(X^2)^T ----------------
    f32x4 accm[2][4], accv[2][4];   // [rt][nt]
    #pragma unroll
    for (int rt = 0; rt < 2; ++rt)
        #pragma unroll
        for (int nt = 0; nt < 4; ++nt) {
            accm[rt][nt] = (f32x4)0.f;
            accv[rt][nt] = (f32x4)0.f;
        }

    #pragma unroll
    for (int ks = 0; ks < 4; ++ks) {
        bf16x8 xb[2], xq[2];
        #pragma unroll
        for (int rt = 0; rt < 2; ++rt) {
            const float* xp = X + (size_t)(row0 + rt * 16 + lcol) * D0 + ks * 32 + lk * 8;
            float4 a = *(const float4*)xp;
            float4 b = *(const float4*)(xp + 4);
            u32x4 um, uq;
            um[0] = cvt_pk_bf16(a.x, a.y);
            um[1] = cvt_pk_bf16(a.z, a.w);
            um[2] = cvt_pk_bf16(b.x, b.y);
            um[3] = cvt_pk_bf16(b.z, b.w);
            uq[0] = cvt_pk_bf16(a.x * a.x, a.y * a.y);
            uq[1] = cvt_pk_bf16(a.z * a.z, a.w * a.w);
            uq[2] = cvt_pk_bf16(b.x * b.x, b.y * b.y);
            uq[3] = cvt_pk_bf16(b.z * b.z, b.w * b.w);
            xb[rt] = __builtin_bit_cast(bf16x8, um);
            xq[rt] = __builtin_bit_cast(bf16x8, uq);
        }
        #pragma unroll
        for (int nt = 0; nt < 4; ++nt) {
            int f = (w * 4 + nt) * 4 + ks;
            bf16x8 amu = *(const bf16x8*)(ws + (size_t)(f * 64 + lane) * 8);
            bf16x8 avr = *(const bf16x8*)(ws + WS_W1VAR + (size_t)(f * 64 + lane) * 8);
            #pragma unroll
            for (int rt = 0; rt < 2; ++rt) {
                accm[rt][nt] = __builtin_amdgcn_mfma_f32_16x16x32_bf16(amu, xb[rt], accm[rt][nt], 0, 0, 0);
                accv[rt][nt] = __builtin_amdgcn_mfma_f32_16x16x32_bf16(avr, xq[rt], accv[rt][nt], 0, 0, 0);
            }
        }
    }

    // RF-ReLU epilogue: per lane 4 consecutive rf at one row -> b64 LDS writes
    const float SCALE  = 0.08838834764831845f;  // sqrt(2/256)
    const float SCALE2 = 0.0078125f;            // 2/256
    #pragma unroll
    for (int rt = 0; rt < 2; ++rt) {
        int xrow = rt * 16 + lcol;
        int swz  = (xrow & 7) << 3;             // 16B-granule XOR swizzle
        int rowb = xrow * 256;
        #pragma unroll
        for (int nt = 0; nt < 4; ++nt) {
            int rf0 = (w * 4 + nt) * 16 + lk * 4;
            float m1[4], v1[4], t1[4];
            #pragma unroll
            for (int i = 0; i < 4; ++i) {
                float om = accm[rt][nt][i];
                float ov = accv[rt][nt][i];
                bool pos = om > 0.f;
                m1[i] = pos ? SCALE  * om : 0.f;
                v1[i] = pos ? SCALE2 * ov : 0.f;
                t1[i] = fmaf(m1[i], m1[i], v1[i]);   // v1 + m1^2
            }
            uint2 pm, pt, pv;
            pm.x = cvt_pk_bf16(m1[0], m1[1]); pm.y = cvt_pk_bf16(m1[2], m1[3]);
            pt.x = cvt_pk_bf16(t1[0], t1[1]); pt.y = cvt_pk_bf16(t1[2], t1[3]);
            pv.x = cvt_pk_bf16(v1[0], v1[1]); pv.y = cvt_pk_bf16(v1[2], v1[3]);
            int idx = rowb + (rf0 ^ swz);
            *(uint2*)&M1s[idx] = pm;
            *(uint2*)&T1s[idx] = pt;
            *(uint2*)&V1s[idx] = pv;
        }
    }

    __syncthreads();

    // ---------------- Layer 2: W2·slab^T moment GEMMs (K=256) ---------------
    f32x4 m2a[2], v2a[2];
    #pragma unroll
    for (int rt = 0; rt < 2; ++rt) { m2a[rt] = (f32x4)0.f; v2a[rt] = (f32x4)0.f; }

    #pragma unroll
    for (int ks = 0; ks < 8; ++ks) {
        int f = w * 8 + ks;
        bf16x8 amu = *(const bf16x8*)(ws + WS_W2MU  + (size_t)(f * 64 + lane) * 8);
        bf16x8 avr = *(const bf16x8*)(ws + WS_W2VAR + (size_t)(f * 64 + lane) * 8);
        bf16x8 asq = *(const bf16x8*)(ws + WS_W2SQ  + (size_t)(f * 64 + lane) * 8);
        #pragma unroll
        for (int rt = 0; rt < 2; ++rt) {
            int xrow = rt * 16 + lcol;
            int base = xrow * 256 + ((ks * 32 + lk * 8) ^ ((xrow & 7) << 3));
            bf16x8 bm = *(const bf16x8*)&M1s[base];
            bf16x8 bt = *(const bf16x8*)&T1s[base];
            bf16x8 bv = *(const bf16x8*)&V1s[base];
            m2a[rt] = __builtin_amdgcn_mfma_f32_16x16x32_bf16(amu, bm, m2a[rt], 0, 0, 0);
            v2a[rt] = __builtin_amdgcn_mfma_f32_16x16x32_bf16(avr, bt, v2a[rt], 0, 0, 0);
            v2a[rt] = __builtin_amdgcn_mfma_f32_16x16x32_bf16(asq, bv, v2a[rt], 0, 0, 0);
        }
    }

    __syncthreads();   // all layer-2 LDS reads done before slab reuse

    // ---------------- Transpose (p, p*m) through LDS ------------------------
    // C layout: value (rt,i) lives at X-row rt*16+lcol, d1 = w*16 + lk*4 + i
    float* Pl = (float*)sh;            // [32][65]
    float* Ml = Pl + BM * 65;          // [32][65]
    #pragma unroll
    for (int rt = 0; rt < 2; ++rt) {
        int xrow = rt * 16 + lcol;
        int d1   = w * 16 + lk * 4;
        #pragma unroll
        for (int i = 0; i < 4; ++i) {
            float p = 1.0f / (v2a[rt][i] + EPSF);
            Pl[xrow * 65 + d1 + i] = p;
            Ml[xrow * 65 + d1 + i] = p * m2a[rt][i];
        }
    }

    __syncthreads();

    // ---------------- Row-coalesced scatter ---------------------------------
    // wave w handles rows w*8 .. w*8+7; per instruction: one uniform row,
    // 64 lanes = 64 consecutive floats = 256B dense region
    #pragma unroll
    for (int r = 0; r < 8; ++r) {
        int row = w * 8 + r;
        int g   = __builtin_amdgcn_readfirstlane(Xidx[row0 + row]);
        float pv = Pl[row * 65 + lane];
        float mv = Ml[row * 65 + lane];
        atomicAdd(accP + (size_t)g * D1 + lane, pv);
        atomicAdd(accM + (size_t)g * D1 + lane, mv);
    }
}

__global__ void dgp_finalize(float* __restrict__ accM,
                             float* __restrict__ accP, int total)
{
    int idx = blockIdx.x * blockDim.x + threadIdx.x;
    if (idx < total) {
        float var = 1.0f / (accP[idx] + EPSF);   // p_sum = seg_sum + EPS
        accP[idx] = var;                         // embedd_vars
        accM[idx] = accM[idx] * var;             // embedd_means
    }
}

extern "C" void kernel_launch(void* const* d_in, const int* in_sizes, int n_in,
                              void* d_out, int out_size, void* d_ws, size_t ws_size,
                              hipStream_t stream)
{
    const float* X     = (const float*)d_in[0];
    const int*   Xidx  = (const int*)d_in[1];
    const float* W1mu  = (const float*)d_in[2];
    const float* W1var = (const float*)d_in[3];
    const float* W2mu  = (const float*)d_in[4];
    const float* W2var = (const float*)d_in[5];

    const int N = in_sizes[0] / D0;            // 262144
    const int U = out_size / (2 * D1);         // 50000
    float* out  = (float*)d_out;
    float* accM = out;                          // means region
    float* accP = out + (size_t)U * D1;         // vars region
    ushort* ws  = (ushort*)d_ws;

    // harness does not re-poison between replays: re-zero accumulators
    hipMemsetAsync(d_out, 0, (size_t)out_size * sizeof(float), stream);

    convert_w<<<56, 256, 0, stream>>>(W1mu, W1var, W2mu, W2var, ws);

    dgp_mfma<<<N / BM, NT, 0, stream>>>(X, Xidx, ws, accM, accP);

    const int total = U * D1;
    dgp_finalize<<<(total + 255) / 256, 256, 0, stream>>>(accM, accP, total);
}

// Round 5
// 196.641 us; speedup vs baseline: 2.5076x; 1.0460x over previous
//
#include <hip/hip_runtime.h>

#define EPSF 1e-8f

constexpr int D0 = 128;   // input dim
constexpr int R  = 256;   // random features
constexpr int D1 = 64;    // output dim
constexpr int BM = 32;    // rows per block
constexpr int NT = 256;   // threads per block (4 waves)

typedef __attribute__((ext_vector_type(8))) short  bf16x8;
typedef __attribute__((ext_vector_type(4))) float  f32x4;
typedef __attribute__((ext_vector_type(4))) uint   u32x4;

// ws layout (ushort elements): bf16 weights in MFMA fragment order
//   [0]      w1mu  frags (64 frags)
//   [32768]  w1var frags
//   [65536]  w2mu  frags (32 frags)          -> m2
//   [81920]  w2c   frags (= w2var + w2mu^2)  -> v2, multiplies v1
//   [98304]  w2var frags                     -> v2, multiplies m1^2
constexpr int WS_W1VAR = 32768;
constexpr int WS_W2MU  = 65536;
constexpr int WS_W2C   = 81920;
constexpr int WS_W2VAR = 98304;

__device__ __forceinline__ ushort f2bf(float x) {
    uint32_t u = __builtin_bit_cast(uint32_t, x);
    u += 0x7FFFu + ((u >> 16) & 1u);          // round-to-nearest-even
    return (ushort)(u >> 16);
}

// packed f32x2 -> bf16x2 (RNE), 1 VALU inst
__device__ __forceinline__ uint cvt_pk_bf16(float lo, float hi) {
    uint r;
    asm("v_cvt_pk_bf16_f32 %0, %1, %2" : "=v"(r) : "v"(lo), "v"(hi));
    return r;
}

// elementwise square of a bf16x8 fragment (bf16->f32 is a shift; 5 VALU/uint)
__device__ __forceinline__ bf16x8 sq_bf16x8(bf16x8 a) {
    u32x4 u = __builtin_bit_cast(u32x4, a);
    u32x4 r;
    #pragma unroll
    for (int i = 0; i < 4; ++i) {
        float lo = __builtin_bit_cast(float, u[i] << 16);
        float hi = __builtin_bit_cast(float, u[i] & 0xFFFF0000u);
        r[i] = cvt_pk_bf16(lo * lo, hi * hi);
    }
    return __builtin_bit_cast(bf16x8, r);
}

// --- pre-kernel: convert weights to bf16 in MFMA fragment order ------------
// frag: lane l, elem j -> W[row = base16 + (l&15)][k = k0 + (l>>4)*8 + j]
__global__ void convert_w(const float* __restrict__ W1mu,
                          const float* __restrict__ W1var,
                          const float* __restrict__ W2mu,
                          const float* __restrict__ W2var,
                          ushort* __restrict__ ws)
{
    int tid = blockIdx.x * 256 + threadIdx.x;
    if (tid < 8192) {                       // layer 1: 2 mats * 64 frags * 64 lanes
        int m    = tid >> 12;               // 0=mu 1=var
        int f    = (tid >> 6) & 63;         // frag = nt*4 + ks
        int lane = tid & 63;
        int nt = f >> 2, ks = f & 3;
        int col = nt * 16 + (lane & 15);    // rf index (W1 row)
        int k0  = ks * 32 + (lane >> 4) * 8;
        const float* src = (m ? W1var : W1mu) + (size_t)col * D0 + k0;
        ushort* dst = ws + (m ? WS_W1VAR : 0) + (size_t)(f * 64 + lane) * 8;
        #pragma unroll
        for (int j = 0; j < 8; ++j) dst[j] = f2bf(src[j]);
    } else if (tid < 8192 + 3 * 2048) {     // layer 2: 3 mats * 32 frags * 64 lanes
        int t2   = tid - 8192;
        int m    = t2 >> 11;                // 0=mu 1=c 2=var
        int f    = (t2 >> 6) & 31;          // frag = nt*8 + ks
        int lane = t2 & 63;
        int nt = f >> 3, ks = f & 7;
        int col = nt * 16 + (lane & 15);    // d1 index (W2 row)
        int k0  = ks * 32 + (lane >> 4) * 8;
        const float* smu = W2mu  + (size_t)col * R + k0;
        const float* svr = W2var + (size_t)col * R + k0;
        ushort* dst = ws + WS_W2MU + m * 16384 + (size_t)(f * 64 + lane) * 8;
        #pragma unroll
        for (int j = 0; j < 8; ++j) {
            float v;
            if (m == 0)      v = smu[j];
            else if (m == 1) v = fmaf(smu[j], smu[j], svr[j]);  // var + mu^2
            else             v = svr[j];
            dst[j] = f2bf(v);
        }
    }
}

// --- fused main kernel ------------------------------------------------------
// Operand-swapped GEMMs (D = W·X^T). Two bf16 slabs (32 KB) -> 4 blocks/CU.
// v2 = v1·(W2var+W2mu^2) + m1^2·W2var, with m1^2 squared on the fly.
__global__ __launch_bounds__(NT, 4)
void dgp_mfma(const float* __restrict__ X,
              const int*   __restrict__ Xidx,
              const ushort* __restrict__ ws,
              float* __restrict__ accM,
              float* __restrict__ accP)
{
    // phase A: 2 bf16 tiles [32][256] XOR-swizzled (32 KB)
    // phase B: aliased as 2 f32 arrays [32][65] for the scatter transpose
    __shared__ __align__(16) ushort sh[2 * BM * R];
    ushort* M1s = sh;
    ushort* V1s = sh + BM * R;

    const int t    = threadIdx.x;
    const int lane = t & 63;
    const int w    = t >> 6;         // wave 0..3
    const int row0 = blockIdx.x * BM;
    const int lcol = lane & 15;      // X-row within 16-tile (B-frag col / C col)
    const int lk   = lane >> 4;      // 0..3 (k-group / C row group)

    // ---------------- Layer 1: W1·X^T (mu) and W1var·(X^2)^T ----------------
    f32x4 accm[2][4], accv[2][4];   // [rt][nt]
    #pragma unroll
    for (int rt = 0; rt < 2; ++rt)
        #pragma unroll
        for (int nt = 0; nt < 4; ++nt) {
            accm[rt][nt] = (f32x4)0.f;
            accv[rt][nt] = (f32x4)0.f;
        }

    #pragma unroll
    for (int ks = 0; ks < 4; ++ks) {
        bf16x8 xb[2], xq[2];
        #pragma unroll
        for (int rt = 0; rt < 2; ++rt) {
            const float* xp = X + (size_t)(row0 + rt * 16 + lcol) * D0 + ks * 32 + lk * 8;
            float4 a = *(const float4*)xp;
            float4 b = *(const float4*)(xp + 4);
            u32x4 um, uq;
            um[0] = cvt_pk_bf16(a.x, a.y);
            um[1] = cvt_pk_bf16(a.z, a.w);
            um[2] = cvt_pk_bf16(b.x, b.y);
            um[3] = cvt_pk_bf16(b.z, b.w);
            uq[0] = cvt_pk_bf16(a.x * a.x, a.y * a.y);
            uq[1] = cvt_pk_bf16(a.z * a.z, a.w * a.w);
            uq[2] = cvt_pk_bf16(b.x * b.x, b.y * b.y);
            uq[3] = cvt_pk_bf16(b.z * b.z, b.w * b.w);
            xb[rt] = __builtin_bit_cast(bf16x8, um);
            xq[rt] = __builtin_bit_cast(bf16x8, uq);
        }
        #pragma unroll
        for (int nt = 0; nt < 4; ++nt) {
            int f = (w * 4 + nt) * 4 + ks;
            bf16x8 amu = *(const bf16x8*)(ws + (size_t)(f * 64 + lane) * 8);
            bf16x8 avr = *(const bf16x8*)(ws + WS_W1VAR + (size_t)(f * 64 + lane) * 8);
            #pragma unroll
            for (int rt = 0; rt < 2; ++rt) {
                accm[rt][nt] = __builtin_amdgcn_mfma_f32_16x16x32_bf16(amu, xb[rt], accm[rt][nt], 0, 0, 0);
                accv[rt][nt] = __builtin_amdgcn_mfma_f32_16x16x32_bf16(avr, xq[rt], accv[rt][nt], 0, 0, 0);
            }
        }
    }

    // RF-ReLU epilogue: per lane 4 consecutive rf at one row -> b64 LDS writes
    const float SCALE  = 0.08838834764831845f;  // sqrt(2/256)
    const float SCALE2 = 0.0078125f;            // 2/256
    #pragma unroll
    for (int rt = 0; rt < 2; ++rt) {
        int xrow = rt * 16 + lcol;
        int swz  = (xrow & 7) << 3;             // 16B-granule XOR swizzle
        int rowb = xrow * 256;
        #pragma unroll
        for (int nt = 0; nt < 4; ++nt) {
            int rf0 = (w * 4 + nt) * 16 + lk * 4;
            float m1[4], v1[4];
            #pragma unroll
            for (int i = 0; i < 4; ++i) {
                float om = accm[rt][nt][i];
                float ov = accv[rt][nt][i];
                bool pos = om > 0.f;
                m1[i] = pos ? SCALE  * om : 0.f;
                v1[i] = pos ? SCALE2 * ov : 0.f;
            }
            uint2 pm, pv;
            pm.x = cvt_pk_bf16(m1[0], m1[1]); pm.y = cvt_pk_bf16(m1[2], m1[3]);
            pv.x = cvt_pk_bf16(v1[0], v1[1]); pv.y = cvt_pk_bf16(v1[2], v1[3]);
            int idx = rowb + (rf0 ^ swz);
            *(uint2*)&M1s[idx] = pm;
            *(uint2*)&V1s[idx] = pv;
        }
    }

    __syncthreads();

    // ---------------- Layer 2: W2·slab^T moment GEMMs (K=256) ---------------
    f32x4 m2a[2], v2a[2];
    #pragma unroll
    for (int rt = 0; rt < 2; ++rt) { m2a[rt] = (f32x4)0.f; v2a[rt] = (f32x4)0.f; }

    #pragma unroll
    for (int ks = 0; ks < 8; ++ks) {
        int f = w * 8 + ks;
        bf16x8 amu = *(const bf16x8*)(ws + WS_W2MU  + (size_t)(f * 64 + lane) * 8);
        bf16x8 ac  = *(const bf16x8*)(ws + WS_W2C   + (size_t)(f * 64 + lane) * 8);
        bf16x8 avr = *(const bf16x8*)(ws + WS_W2VAR + (size_t)(f * 64 + lane) * 8);
        #pragma unroll
        for (int rt = 0; rt < 2; ++rt) {
            int xrow = rt * 16 + lcol;
            int base = xrow * 256 + ((ks * 32 + lk * 8) ^ ((xrow & 7) << 3));
            bf16x8 bm  = *(const bf16x8*)&M1s[base];
            bf16x8 bv  = *(const bf16x8*)&V1s[base];
            bf16x8 bms = sq_bf16x8(bm);
            m2a[rt] = __builtin_amdgcn_mfma_f32_16x16x32_bf16(amu, bm,  m2a[rt], 0, 0, 0);
            v2a[rt] = __builtin_amdgcn_mfma_f32_16x16x32_bf16(ac,  bv,  v2a[rt], 0, 0, 0);
            v2a[rt] = __builtin_amdgcn_mfma_f32_16x16x32_bf16(avr, bms, v2a[rt], 0, 0, 0);
        }
    }

    __syncthreads();   // all layer-2 LDS reads done before slab reuse

    // ---------------- Transpose (p, p*m) through LDS ------------------------
    // C layout: value (rt,i) lives at X-row rt*16+lcol, d1 = w*16 + lk*4 + i
    float* Pl = (float*)sh;            // [32][65]
    float* Ml = Pl + BM * 65;          // [32][65]
    #pragma unroll
    for (int rt = 0; rt < 2; ++rt) {
        int xrow = rt * 16 + lcol;
        int d1   = w * 16 + lk * 4;
        #pragma unroll
        for (int i = 0; i < 4; ++i) {
            float p = 1.0f / (v2a[rt][i] + EPSF);
            Pl[xrow * 65 + d1 + i] = p;
            Ml[xrow * 65 + d1 + i] = p * m2a[rt][i];
        }
    }

    __syncthreads();

    // ---------------- Row-coalesced scatter ---------------------------------
    // wave w handles rows w*8 .. w*8+7; per instruction: one uniform row,
    // 64 lanes = 64 consecutive floats = 256B dense region
    #pragma unroll
    for (int r = 0; r < 8; ++r) {
        int row = w * 8 + r;
        int g   = __builtin_amdgcn_readfirstlane(Xidx[row0 + row]);
        float pv = Pl[row * 65 + lane];
        float mv = Ml[row * 65 + lane];
        atomicAdd(accP + (size_t)g * D1 + lane, pv);
        atomicAdd(accM + (size_t)g * D1 + lane, mv);
    }
}

__global__ void dgp_finalize(float* __restrict__ accM,
                             float* __restrict__ accP, int total)
{
    int idx = blockIdx.x * blockDim.x + threadIdx.x;
    if (idx < total) {
        float var = 1.0f / (accP[idx] + EPSF);   // p_sum = seg_sum + EPS
        accP[idx] = var;                         // embedd_vars
        accM[idx] = accM[idx] * var;             // embedd_means
    }
}

extern "C" void kernel_launch(void* const* d_in, const int* in_sizes, int n_in,
                              void* d_out, int out_size, void* d_ws, size_t ws_size,
                              hipStream_t stream)
{
    const float* X     = (const float*)d_in[0];
    const int*   Xidx  = (const int*)d_in[1];
    const float* W1mu  = (const float*)d_in[2];
    const float* W1var = (const float*)d_in[3];
    const float* W2mu  = (const float*)d_in[4];
    const float* W2var = (const float*)d_in[5];

    const int N = in_sizes[0] / D0;            // 262144
    const int U = out_size / (2 * D1);         // 50000
    float* out  = (float*)d_out;
    float* accM = out;                          // means region
    float* accP = out + (size_t)U * D1;         // vars region
    ushort* ws  = (ushort*)d_ws;

    // harness does not re-poison between replays: re-zero accumulators
    hipMemsetAsync(d_out, 0, (size_t)out_size * sizeof(float), stream);

    convert_w<<<56, 256, 0, stream>>>(W1mu, W1var, W2mu, W2var, ws);

    dgp_mfma<<<N / BM, NT, 0, stream>>>(X, Xidx, ws, accM, accP);

    const int total = U * D1;
    dgp_finalize<<<(total + 255) / 256, 256, 0, stream>>>(accM, accP, total);
}